// Round 6
// baseline (268.571 us; speedup 1.0000x reference)
//
#include <hip/hip_runtime.h>

typedef unsigned long long u64;
typedef unsigned int u32;
typedef unsigned short u16;

#define HW 3136      // 56*56
#define NPIX 100352  // 32*3136
#define XPITCH 3600  // padded 60*60 pixels per image

// ---- pack weights into [tap][co][8 x u32] + per-(co,tap) popcount ----------
__global__ __launch_bounds__(256) void pack_w_kernel(const float* __restrict__ W,
                                                     u32* __restrict__ wp32,
                                                     u16* __restrict__ pw) {
    int t = blockIdx.x * 256 + threadIdx.x;   // co*9 + tap, 2304 total (9 blocks)
    int co = t / 9, tap = t % 9;
    u64 b[4] = {0, 0, 0, 0};
    for (int ci = 0; ci < 256; ++ci) {
        float v = W[(size_t)(co * 256 + ci) * 9 + tap];
        if (v >= 0.f) b[ci >> 6] |= 1ull << (ci & 63);
    }
    u32* dst = wp32 + ((size_t)tap * 256 + co) * 8;
    #pragma unroll
    for (int j = 0; j < 4; ++j) {
        dst[2 * j]     = (u32)b[j];
        dst[2 * j + 1] = (u32)(b[j] >> 32);
    }
    pw[co * 9 + tap] = (u16)(__popcll(b[0]) + __popcll(b[1]) + __popcll(b[2]) + __popcll(b[3]));
}

// ---- bias table: bias[mi][co] = 256*Vcount + 2*sum_invalid popc(w) ---------
__global__ void bias_kernel(const u16* __restrict__ pw, u16* __restrict__ bias) {
    int mi = blockIdx.x;          // border class 0..8
    int co = threadIdx.x;
    int rm = mi / 3, cm = mi % 3;
    int vr = rm == 0 ? 6 : (rm == 2 ? 3 : 7);
    int vc = cm == 0 ? 6 : (cm == 2 ? 3 : 7);
    int corr = 0;
    for (int kh = 0; kh < 3; ++kh)
        for (int kw = 0; kw < 3; ++kw)
            if (!(((vr >> kh) & 1) && ((vc >> kw) & 1)))
                corr += pw[co * 9 + kh * 3 + kw];
    bias[mi * 256 + co] = (u16)(256 * __popc(vr) * __popc(vc) + 2 * corr);
}

// ---- pack activations into zero-padded [n][60][60][4 x u64] ----------------
__global__ __launch_bounds__(256) void pack_x_kernel(const float* __restrict__ x,
                                                     u64* __restrict__ xpad) {
    int s = blockIdx.x * 256 + threadIdx.x;   // pixel in [0, 100352)
    int word = blockIdx.y;                    // 0..3 (64 channels each)
    int n = s / HW, hw = s % HW;
    int h = hw / 56, w = hw % 56;
    const float* px = x + (size_t)(n * 256 + word * 64) * HW + hw;
    u64 b = 0;
    #pragma unroll 8
    for (int ci = 0; ci < 64; ++ci) {
        float v = px[(size_t)ci * HW];
        if (v >= 0.f) b |= 1ull << ci;
    }
    xpad[((size_t)n * XPITCH + (h + 2) * 60 + (w + 2)) * 4 + word] = b;
}

// ---- XNOR conv: weights in SGPRs, padded x, pure xor+bcnt inner loop -------
#define CPT 8   // channels per thread
__global__ __launch_bounds__(256) void conv_kernel(const u32* __restrict__ xpad,
                                                   const u32* __restrict__ wp32,
                                                   const u16* __restrict__ bias,
                                                   short* __restrict__ y) {
    int s = blockIdx.x * 256 + threadIdx.x;   // pixel
    int n = s / HW, hw = s % HW;
    int h = hw / 56, w = hw % 56;
    int co0 = blockIdx.y * CPT;

    const u32* xb = xpad + ((size_t)n * XPITCH + h * 60 + w) * 8;  // tap (0,0) addr

    int acc[CPT];
    #pragma unroll
    for (int c = 0; c < CPT; ++c) acc[c] = 0;

    for (int kh = 0; kh < 3; ++kh) {          // runtime loops, no border logic at all
        for (int kw = 0; kw < 3; ++kw) {
            const u32* px = xb + (kh * 120 + kw * 2) * 8;          // always in-bounds
            uint4 a = *(const uint4*)(px);
            uint4 b = *(const uint4*)(px + 4);
            const u32* wt = wp32 + (((kh * 3 + kw) * 256 + co0) * 8);  // uniform -> s_load
            #pragma unroll
            for (int c = 0; c < CPT; ++c) {
                const u32* wc8 = wt + c * 8;
                acc[c] += __popc(a.x ^ wc8[0]);
                acc[c] += __popc(a.y ^ wc8[1]);
                acc[c] += __popc(a.z ^ wc8[2]);
                acc[c] += __popc(a.w ^ wc8[3]);
                acc[c] += __popc(b.x ^ wc8[4]);
                acc[c] += __popc(b.y ^ wc8[5]);
                acc[c] += __popc(b.z ^ wc8[6]);
                acc[c] += __popc(b.w ^ wc8[7]);
            }
        }
    }

    int rm = (h < 2) ? 0 : (h > 53 ? 2 : 1);
    int cm = (w < 2) ? 0 : (w > 53 ? 2 : 1);
    int mi = rm * 3 + cm;
    uint4 bv = *(const uint4*)(bias + (size_t)mi * 256 + co0);     // 8 x u16, 16B aligned
    u32 bw[4] = {bv.x, bv.y, bv.z, bv.w};
    short* yo = y + ((size_t)n * 256 + co0) * HW + hw;
    #pragma unroll
    for (int c = 0; c < CPT; ++c) {
        int bval = (int)((bw[c >> 1] >> ((c & 1) * 16)) & 0xffff);
        yo[(size_t)c * HW] = (short)(bval - 2 * acc[c]);
    }
}

// ---- exact per-plane stats: one block per (n, c) plane ---------------------
__global__ __launch_bounds__(256) void stats1_kernel(const short* __restrict__ y,
                                                     long long* __restrict__ part) {
    int pl = blockIdx.x;                      // n*256 + c
    const short* p = y + (size_t)pl * HW;
    int tid = threadIdx.x;
    int a1 = 0; long long q1 = 0;
    for (int i = tid; i < 392; i += 256) {    // 392 short8 per plane
        int4 v = *(const int4*)(p + i * 8);
        int vs[4] = {v.x, v.y, v.z, v.w};
        int a = 0, q = 0;
        #pragma unroll
        for (int j = 0; j < 4; ++j) {
            int lo = (short)(vs[j] & 0xffff);
            int hi = (short)(vs[j] >> 16);
            a += lo + hi;
            q += lo * lo + hi * hi;
        }
        a1 += a; q1 += q;
    }
    long long s1 = a1, s2 = q1;
    #pragma unroll
    for (int off = 32; off > 0; off >>= 1) {
        s1 += __shfl_down(s1, off);
        s2 += __shfl_down(s2, off);
    }
    __shared__ long long ls1[4], ls2[4];
    if ((tid & 63) == 0) { ls1[tid >> 6] = s1; ls2[tid >> 6] = s2; }
    __syncthreads();
    if (tid == 0) {
        part[(size_t)pl * 2]     = ls1[0] + ls1[1] + ls1[2] + ls1[3];
        part[(size_t)pl * 2 + 1] = ls2[0] + ls2[1] + ls2[2] + ls2[3];
    }
}

__global__ void stats2_kernel(const long long* __restrict__ part,
                              const float* __restrict__ gamma,
                              const float* __restrict__ beta,
                              float2* __restrict__ sc) {
    int c = threadIdx.x;
    long long S1i = 0, S2i = 0;
    for (int n = 0; n < 32; ++n) {
        S1i += part[(size_t)(n * 256 + c) * 2];
        S2i += part[(size_t)(n * 256 + c) * 2 + 1];
    }
    double S1 = (double)S1i, S2 = (double)S2i;
    double cnt = 100352.0;
    double mean = S1 / cnt;
    double var = S2 / cnt - mean * mean;
    float a = gamma[c] * rsqrtf((float)var + 1e-5f);
    float b = beta[c] - (float)mean * a;
    sc[c] = make_float2(a, b);
}

// ---- normalize + tanh, vectorized ------------------------------------------
__global__ __launch_bounds__(256) void norm_kernel(const short* __restrict__ y,
                                                   const float2* __restrict__ sc,
                                                   float* __restrict__ out) {
    size_t i = ((size_t)blockIdx.x * 256 + threadIdx.x) * 8;   // 8-groups never cross a plane
    int c = (int)((i / HW) & 255);
    float2 s = sc[c];
    int4 v = *(const int4*)(y + i);
    int vs[4] = {v.x, v.y, v.z, v.w};
    float r[8];
    #pragma unroll
    for (int j = 0; j < 4; ++j) {
        short lo = (short)(vs[j] & 0xffff);
        short hi = (short)(vs[j] >> 16);
        r[2 * j]     = tanhf(s.x * (float)lo + s.y);
        r[2 * j + 1] = tanhf(s.x * (float)hi + s.y);
    }
    *(float4*)(out + i)     = make_float4(r[0], r[1], r[2], r[3]);
    *(float4*)(out + i + 4) = make_float4(r[4], r[5], r[6], r[7]);
}

extern "C" void kernel_launch(void* const* d_in, const int* in_sizes, int n_in,
                              void* d_out, int out_size, void* d_ws, size_t ws_size,
                              hipStream_t stream) {
    const float* x     = (const float*)d_in[0];
    const float* W     = (const float*)d_in[1];
    const float* gamma = (const float*)d_in[2];
    const float* beta  = (const float*)d_in[3];
    float* out = (float*)d_out;

    char* ws = (char*)d_ws;
    short* y        = (short*)ws;                      // 51,380,224 B
    u64*  xpad      = (u64*)(ws + 51380224);           //  3,686,400 B
    u32*  wp32      = (u32*)(ws + 55066624);           //     73,728 B
    u16*  pw        = (u16*)(ws + 55140352);           //      4,608 B
    u16*  bias      = (u16*)(ws + 55144960);           //      4,608 B
    float2* sc      = (float2*)(ws + 55149568);        //      2,048 B
    long long* part = (long long*)(ws + 55151616);     //    131,072 B

    (void)hipMemsetAsync(xpad, 0, 3686400, stream);    // zero padding borders
    pack_w_kernel<<<9, 256, 0, stream>>>(W, wp32, pw);
    bias_kernel<<<9, 256, 0, stream>>>(pw, bias);
    pack_x_kernel<<<dim3(392, 4), 256, 0, stream>>>(x, xpad);
    conv_kernel<<<dim3(392, 32), 256, 0, stream>>>((const u32*)xpad, wp32, bias, y);
    stats1_kernel<<<8192, 256, 0, stream>>>(y, part);
    stats2_kernel<<<1, 256, 0, stream>>>(part, gamma, beta, sc);
    norm_kernel<<<12544, 256, 0, stream>>>(y, sc, out);
}